// Round 7
// baseline (12177.515 us; speedup 1.0000x reference)
//
#include <hip/hip_runtime.h>
#include <cstdint>
#include <cstddef>

// Problem constants
#define B_    16
#define T_    32
#define H_    512
#define P_    1024        // 32*32 spatial
#define NPOS  16384       // B_*P_
#define NG    2048        // 4*H_

typedef __attribute__((ext_vector_type(8))) short short8;
typedef __attribute__((ext_vector_type(4))) float f32x4;

__device__ __forceinline__ unsigned short f2bf(float f) {
  uint32_t u = __float_as_uint(f);
  u += 0x7fffu + ((u >> 16) & 1u);     // RNE
  return (unsigned short)(u >> 16);
}
__device__ __forceinline__ float bflo(uint32_t u) { return __uint_as_float(u << 16); }
__device__ __forceinline__ float bfhi(uint32_t u) { return __uint_as_float(u & 0xffff0000u); }

__device__ __forceinline__ float sigf(float x) {
  return __builtin_amdgcn_rcpf(1.0f + __expf(-x));
}
__device__ __forceinline__ float tanhf_(float x) {
  return 1.0f - 2.0f * __builtin_amdgcn_rcpf(__expf(2.0f * x) + 1.0f);
}

__device__ __forceinline__ void gload_lds16(const void* g, void* l) {
  __builtin_amdgcn_global_load_lds(
      (const __attribute__((address_space(1))) void*)g,
      (__attribute__((address_space(3))) void*)l, 16, 0, 0);
}

// ---------------- repack kernels ----------------
// Wp[r][k] = bf16(Wc[o][1+k]),  r = ch*4+g,  o = g*512+ch  (k-contiguous rows)
__global__ void repack_w(const float* __restrict__ Wc, const float* __restrict__ bconv,
                         unsigned short* __restrict__ Wp, float* __restrict__ w0x,
                         float* __restrict__ bx) {
  int idx = blockIdx.x * 256 + threadIdx.x;       // 2048*512 exact
  int r = idx >> 9, k = idx & 511;
  int ch = r >> 2, g = r & 3;
  int o = g * 512 + ch;
  Wp[idx] = f2bf(Wc[o * 513 + 1 + k]);
  if (k == 0) { w0x[r] = Wc[o * 513]; bx[r] = bconv[o]; }
}

// wpp[j][c] = W_post[0][c][j],  j = dy*3+dx  (c-contiguous)
__global__ void repack_wpost(const float* __restrict__ Wpost, float* __restrict__ wpp) {
  int idx = blockIdx.x * 256 + threadIdx.x;
  if (idx >= 9 * 512) return;
  int j = idx >> 9, c = idx & 511;
  wpp[idx] = Wpost[c * 9 + j];
}

// ---------------- fused gates-GEMM + LSTM pointwise ----------------
// Occupancy is the ONLY variable that has moved lstm_step across 7 configs
// (1 wave/SIMD->76us, 2->57-59 across three schedules, 3->50.6-53.4).
// This round: BK=32 single-buffer -> 24 KB LDS -> 5 blocks/CU (VGPR 92 allows
// 5 waves/SIMD). Same verified 2-barrier loop, T1 XCD swizzle (FETCH 76->33MB
// verified), bank-even chunk-XOR (key (row>>1)&3 for 64B rows: 8 distinct 16B
// slots per 64-lane b128 read -- same evenness as the verified BK=64 layout).
// Also fused: 3x3 stencil of step t-1 (16 threads, overlapped with stage-0
// latency) -- removes the conv_st launch.
__global__ __launch_bounds__(256, 5)
void lstm_step(const unsigned short* __restrict__ Wp,
               const unsigned short* __restrict__ hprev,
               unsigned short* __restrict__ hnext,
               _Float16* __restrict__ Cst,
               const float* __restrict__ w0x, const float* __restrict__ bxv,
               const float* __restrict__ xin,
               const float* __restrict__ u, const float* __restrict__ bpost,
               float* __restrict__ out, int t) {
  __shared__ unsigned short As[256 * 32];   // W tile  [row][k], 64B rows, XOR chunks (16 KB)
  __shared__ unsigned short Bs[128 * 32];   // h tile  [pos][k], 64B rows, XOR chunks (8 KB)

  const int tid = threadIdx.x;
  const int lane = tid & 63;
  const int wv = tid >> 6;
  const int wm = wv >> 1, wn = wv & 1;      // 2x2 waves over 256x128 tile
  const int q = lane >> 4, l = lane & 15;

  // T1 XCD swizzle (verified): each XCD owns 16 contiguous pos-tiles x 8 row-tiles
  const int lid = blockIdx.x;               // 0..1023
  const int xcd = lid & 7;
  const int s   = lid >> 3;                 // 0..127
  const int ny  = xcd * 16 + (s & 15);      // pos-tile 0..127
  const int rx  = s >> 4;                   // row-tile 0..7
  const int r0  = rx * 256;
  const int n0  = ny * 128;
  const int ch0 = rx * 64;

  // staging map: LDS byte j*4096 + tid*16 -> row j*64 + (tid>>2), slot tid&3.
  // slot cp of row r holds global chunk cp ^ ((r>>1)&3)  (= (tid>>3)&3 here;
  // exact since j*64 is even). Pre-swizzled source, linear DMA dest (rule #21).
  const int srow = tid >> 2;                // 0..63
  const int gchunk = (tid & 3) ^ ((tid >> 3) & 3);
  const unsigned short* gA = Wp    + (size_t)(r0 + srow) * 512 + gchunk * 8;
  const unsigned short* gB = hprev + (size_t)(n0 + srow) * 512 + gchunk * 8;
  char* lA = (char*)As + wv * 1024;
  char* lB = (char*)Bs + wv * 1024;

  f32x4 acc[8][4] = {};

  // chunk-0 stage, overlapped with the fused stencil of step t-1
  {
#pragma unroll
    for (int j = 0; j < 4; ++j)
      gload_lds16(gA + (size_t)(j * 64) * 512, lA + j * 4096);
#pragma unroll
    for (int j = 0; j < 2; ++j)
      gload_lds16(gB + (size_t)(j * 64) * 512, lB + j * 4096);
  }
  if (t > 0 && tid < 16) {                  // fused conv_st for step t-1
    int pix = lid * 16 + tid;               // 1024*16 = 16384 exact
    int b = pix >> 10, p = pix & 1023;
    int py = p >> 5, px = p & 31;
    float a = bpost[0];
#pragma unroll
    for (int dy = -1; dy <= 1; ++dy) {
      int nyy = py + dy;
      if ((unsigned)nyy > 31u) continue;
#pragma unroll
      for (int dx = -1; dx <= 1; ++dx) {
        int nx = px + dx;
        if ((unsigned)nx > 31u) continue;
        int j = (dy + 1) * 3 + (dx + 1);
        a += u[((b * 9 + j) << 10) + (nyy << 5) + nx];
      }
    }
    out[((b * T_ + (t - 1)) << 10) + p] = a;
  }
  __syncthreads();

  // fragment slot offset (shorts): global chunk q stored at q ^ ((row>>1)&3);
  // row = base+l with base%16==0 -> key = (l>>1)&3, lane-constant.
  const int cxs = (q ^ ((l >> 1) & 3)) << 3;

  for (int kt = 0; kt < 16; ++kt) {
    short8 af[8], bf_[4];
#pragma unroll
    for (int mi = 0; mi < 8; ++mi) {
      int row = wm * 128 + mi * 16 + l;
      af[mi] = *(const short8*)(As + row * 32 + cxs);
    }
#pragma unroll
    for (int ni = 0; ni < 4; ++ni) {
      int row = wn * 64 + ni * 16 + l;
      bf_[ni] = *(const short8*)(Bs + row * 32 + cxs);
    }
#pragma unroll
    for (int mi = 0; mi < 8; ++mi)
#pragma unroll
      for (int ni = 0; ni < 4; ++ni)
        acc[mi][ni] = __builtin_amdgcn_mfma_f32_16x16x32_bf16(af[mi], bf_[ni], acc[mi][ni], 0, 0, 0);
    __syncthreads();                        // reads done -> safe to overwrite

    if (kt < 15) {
      int kc = (kt + 1) * 32;
#pragma unroll
      for (int j = 0; j < 4; ++j)
        gload_lds16(gA + (size_t)(j * 64) * 512 + kc, lA + j * 4096);
#pragma unroll
      for (int j = 0; j < 2; ++j)
        gload_lds16(gB + (size_t)(j * 64) * 512 + kc, lB + j * 4096);
      __syncthreads();                      // vmcnt drain: next chunk ready
    }
  }

  // ---- epilogue: lane's 4 regs of acc[mi][ni] = (i,f,o,g) for one (ch,pos) ----
  float xv[4]; int posL[4]; size_t cbase[4];
#pragma unroll
  for (int ni = 0; ni < 4; ++ni) {
    posL[ni] = wn * 64 + ni * 16 + l;
    int pos = n0 + posL[ni];
    int b = pos >> 10, p = pos & 1023;
    xv[ni] = xin[((b * T_ + t) << 10) + p];
    cbase[ni] = ((size_t)b << 19) + p;    // b*512*1024 + p
  }
#pragma unroll
  for (int mi = 0; mi < 8; ++mi) {
    int chl = wm * 32 + mi * 4 + q;                    // local ch 0..63
    int rg = r0 + wm * 128 + mi * 16 + q * 4;          // global row of reg0
    float4 w0 = *(const float4*)(w0x + rg);
    float4 bb = *(const float4*)(bxv + rg);
    int ch = ch0 + chl;
#pragma unroll
    for (int ni = 0; ni < 4; ++ni) {
      f32x4 g = acc[mi][ni];
      float gi = g[0] + w0.x * xv[ni] + bb.x;
      float gf = g[1] + w0.y * xv[ni] + bb.y;
      float go = g[2] + w0.z * xv[ni] + bb.z;
      float gg = g[3] + w0.w * xv[ni] + bb.w;
      size_t cidx = cbase[ni] + ((size_t)ch << 10);
      float cold = (float)Cst[cidx];
      float cn = sigf(gf) * cold + sigf(gi) + tanhf_(gg);
      float hn = sigf(go) + tanhf_(cn);
      Cst[cidx] = (_Float16)cn;
      // stash [128 pos][64 ch] shorts = 16 KB, exactly As. Chunk-XOR swizzled
      // (verified: conflicts 4.13M -> 327K).
      As[posL[ni] * 64 + (chl ^ ((posL[ni] & 7) << 3))] = f2bf(hn);
    }
  }
  __syncthreads();
  {
    int pl = tid >> 1;                 // 0..127 local pos
    int cb = (tid & 1) << 2;           // chunk base: 0 or 4 (8-short chunks)
    const unsigned short* srcrow = As + pl * 64;
    unsigned short* dst = hnext + (size_t)(n0 + pl) * 512 + ch0 + (cb << 3);
#pragma unroll
    for (int i = 0; i < 4; ++i)
      ((uint4*)dst)[i] = *(const uint4*)(srcrow + (((cb + i) ^ (pl & 7)) << 3));
  }
}

// ---------------- post conv part 1: u[j][pos] = dot_c(h[pos], wpp[j]) ----------------
// 16 lanes per pixel (wave = 4 pixels), lane owns 32 channels: halves the
// wave-instructions/pixel vs the 64-wide-reduce-for-1-lane version.
__global__ __launch_bounds__(256)
void conv_u(const unsigned short* __restrict__ h, const float* __restrict__ wpp,
            float* __restrict__ u) {
  int wid = blockIdx.x * 4 + (threadIdx.x >> 6);   // wave 0..4095
  int lane = threadIdx.x & 63;
  int sub = lane >> 4;              // pixel within wave
  int sl  = lane & 15;
  int pix = wid * 4 + sub;          // 0..16383
  int c0 = sl << 5;                 // 32 ch per lane
  const uint4* hp = (const uint4*)(h + ((size_t)pix << 9) + c0);
  float a[9] = {};
#pragma unroll
  for (int g = 0; g < 4; ++g) {     // 4 groups of 8 channels
    uint4 hv = hp[g];
    float x0 = bflo(hv.x), x1 = bfhi(hv.x), x2 = bflo(hv.y), x3 = bfhi(hv.y);
    float x4 = bflo(hv.z), x5 = bfhi(hv.z), x6 = bflo(hv.w), x7 = bfhi(hv.w);
    int cg = c0 + g * 8;
#pragma unroll
    for (int j = 0; j < 9; ++j) {
      const float4 wa = *(const float4*)(wpp + (j << 9) + cg);
      const float4 wb = *(const float4*)(wpp + (j << 9) + cg + 4);
      a[j] += x0 * wa.x + x1 * wa.y + x2 * wa.z + x3 * wa.w
            + x4 * wb.x + x5 * wb.y + x6 * wb.z + x7 * wb.w;
    }
  }
  int b = pix >> 10, p = pix & 1023;
  float outv = 0.f;
#pragma unroll
  for (int j = 0; j < 9; ++j) {
    float v = a[j];
    v += __shfl_xor(v, 1, 64);
    v += __shfl_xor(v, 2, 64);
    v += __shfl_xor(v, 4, 64);
    v += __shfl_xor(v, 8, 64);      // 16-lane group sum
    if (sl == j) outv = v;
  }
  if (sl < 9)
    u[((b * 9 + sl) << 10) + p] = outv;
}

// standalone 3x3 stencil (used once, for the final step's output)
__global__ __launch_bounds__(256)
void conv_st(const float* __restrict__ u, const float* __restrict__ bpost,
             float* __restrict__ out, int t) {
  int idx = blockIdx.x * 256 + threadIdx.x;        // 0..16383
  int b = idx >> 10, p = idx & 1023;
  int py = p >> 5, px = p & 31;
  float acc = bpost[0];
#pragma unroll
  for (int dy = -1; dy <= 1; ++dy) {
    int ny = py + dy;
    if ((unsigned)ny > 31u) continue;
#pragma unroll
    for (int dx = -1; dx <= 1; ++dx) {
      int nx = px + dx;
      if ((unsigned)nx > 31u) continue;
      int j = (dy + 1) * 3 + (dx + 1);
      acc += u[((b * 9 + j) << 10) + (ny << 5) + nx];
    }
  }
  out[((b * T_ + t) << 10) + p] = acc;
}

// ---------------- launch ----------------
extern "C" void kernel_launch(void* const* d_in, const int* in_sizes, int n_in,
                              void* d_out, int out_size, void* d_ws, size_t ws_size,
                              hipStream_t stream) {
  const float* x     = (const float*)d_in[0];
  const float* Wconv = (const float*)d_in[1];
  const float* bconv = (const float*)d_in[2];
  const float* Wpost = (const float*)d_in[3];
  const float* bpost = (const float*)d_in[4];
  float* out = (float*)d_out;
  char* ws = (char*)d_ws;

  // workspace layout (bytes)
  unsigned short* h0  = (unsigned short*)(ws);                 // 16 MB
  unsigned short* h1  = (unsigned short*)(ws + 16777216);      // 16 MB
  _Float16*       Cst = (_Float16*)(ws + 33554432);            // 16 MB (fp16 state)
  unsigned short* Wp  = (unsigned short*)(ws + 50331648);      // 2 MB
  float*          w0x = (float*)(ws + 52428800);               // 8 KB
  float*          bx  = (float*)(ws + 52436992);               // 8 KB
  float*          wpp = (float*)(ws + 52445184);               // 18 KB
  float*          u   = (float*)(ws + 52463616);               // 576 KB (16*9*1024 f32)

  hipMemsetAsync(h0, 0, 16777216, stream);
  hipMemsetAsync(Cst, 0, 16777216, stream);
  repack_w<<<4096, 256, 0, stream>>>(Wconv, bconv, Wp, w0x, bx);
  repack_wpost<<<18, 256, 0, stream>>>(Wpost, wpp);

  unsigned short* hp = h0;
  unsigned short* hn = h1;
  for (int t = 0; t < T_; ++t) {
    lstm_step<<<1024, 256, 0, stream>>>(Wp, hp, hn, Cst, w0x, bx, x, u, bpost, out, t);
    conv_u<<<1024, 256, 0, stream>>>(hn, wpp, u);
    unsigned short* tmp = hp; hp = hn; hn = tmp;
  }
  conv_st<<<64, 256, 0, stream>>>(u, bpost, out, T_ - 1);
}

// Round 9
// 2617.366 us; speedup vs baseline: 4.6526x; 4.6526x over previous
//
#include <hip/hip_runtime.h>
#include <cstdint>
#include <cstddef>

// Problem constants
#define B_    16
#define T_    32
#define H_    512
#define P_    1024        // 32*32 spatial
#define NPOS  16384       // B_*P_
#define NG    2048        // 4*H_

typedef __attribute__((ext_vector_type(8))) short short8;
typedef __attribute__((ext_vector_type(4))) float f32x4;

__device__ __forceinline__ unsigned short f2bf(float f) {
  uint32_t u = __float_as_uint(f);
  u += 0x7fffu + ((u >> 16) & 1u);     // RNE
  return (unsigned short)(u >> 16);
}
__device__ __forceinline__ float bflo(uint32_t u) { return __uint_as_float(u << 16); }
__device__ __forceinline__ float bfhi(uint32_t u) { return __uint_as_float(u & 0xffff0000u); }

__device__ __forceinline__ float sigf(float x) {
  return __builtin_amdgcn_rcpf(1.0f + __expf(-x));
}
__device__ __forceinline__ float tanhf_(float x) {
  return 1.0f - 2.0f * __builtin_amdgcn_rcpf(__expf(2.0f * x) + 1.0f);
}

__device__ __forceinline__ void gload_lds16(const void* g, void* l) {
  __builtin_amdgcn_global_load_lds(
      (const __attribute__((address_space(1))) void*)g,
      (__attribute__((address_space(3))) void*)l, 16, 0, 0);
}

// ---------------- repack kernels ----------------
// Wp[r][k] = bf16(Wc[o][1+k]),  r = ch*4+g,  o = g*512+ch  (k-contiguous rows)
__global__ void repack_w(const float* __restrict__ Wc, const float* __restrict__ bconv,
                         unsigned short* __restrict__ Wp, float* __restrict__ w0x,
                         float* __restrict__ bx) {
  int idx = blockIdx.x * 256 + threadIdx.x;       // 2048*512 exact
  int r = idx >> 9, k = idx & 511;
  int ch = r >> 2, g = r & 3;
  int o = g * 512 + ch;
  Wp[idx] = f2bf(Wc[o * 513 + 1 + k]);
  if (k == 0) { w0x[r] = Wc[o * 513]; bx[r] = bconv[o]; }
}

// wpp[j][c] = W_post[0][c][j],  j = dy*3+dx  (c-contiguous)
__global__ void repack_wpost(const float* __restrict__ Wpost, float* __restrict__ wpp) {
  int idx = blockIdx.x * 256 + threadIdx.x;
  if (idx >= 9 * 512) return;
  int j = idx >> 9, c = idx & 511;
  wpp[idx] = Wpost[c * 9 + j];
}

// ---------------- fused gates-GEMM + LSTM pointwise ----------------
// Occupancy ladder: 1 wave/SIMD->76us, 2->50.6-59 (five schedules). R7's 5/SIMD
// attempt spilled acc to scratch (launch_bounds cap 102 < 220 regs needed:
// WRITE_SIZE 33MB->1.1GB). 3 waves/SIMD requires total regs <=170, which the
// 128x64 wave tile's acc[8][4]=128 AGPR forbids. This round: 64x64 wave tile ->
// acc[4][4]=64 AGPR + ~85 VGPR ~= 150 <= 170 -> legitimately 3 waves/SIMD, no
// spill. Block = 4 waves over 128x128, BK=64, 32 KB LDS, same verified
// 2-barrier loop + chunk-XOR layout + T1 XCD swizzle. Tripwire: WRITE_SIZE
// must stay ~33 MB (no scratch).  [Resubmitted verbatim: round-8 bench was an
// infra failure (container acquire), not a kernel result.]
__global__ __launch_bounds__(256, 3)
void lstm_step(const unsigned short* __restrict__ Wp,
               const unsigned short* __restrict__ hprev,
               unsigned short* __restrict__ hnext,
               _Float16* __restrict__ Cst,
               const float* __restrict__ w0x, const float* __restrict__ bxv,
               const float* __restrict__ xin,
               const float* __restrict__ u, const float* __restrict__ bpost,
               float* __restrict__ out, int t) {
  __shared__ unsigned short As[128 * 64];   // W tile  [row][k], 128B rows, XOR chunks (16 KB)
  __shared__ unsigned short Bs[128 * 64];   // h tile  [pos][k], 128B rows, XOR chunks (16 KB)

  const int tid = threadIdx.x;
  const int lane = tid & 63;
  const int wv = tid >> 6;
  const int wm = wv >> 1, wn = wv & 1;      // 2x2 waves over 128x128 tile
  const int q = lane >> 4, l = lane & 15;

  // T1 XCD swizzle (verified: FETCH 76->33 MB): each XCD owns 16 contiguous
  // pos-tiles x all 16 row-tiles -> W (2 MB) + h slice (2 MB) L2-resident.
  const int lid = blockIdx.x;               // 0..2047
  const int xcd = lid & 7;
  const int s   = lid >> 3;                 // 0..255
  const int ny  = xcd * 16 + (s & 15);      // pos-tile 0..127
  const int rx  = s >> 4;                   // row-tile 0..15
  const int r0  = rx * 128;                 // gate-row base
  const int n0  = ny * 128;                 // position base
  const int ch0 = rx * 32;                  // channel base (4 gate-rows/ch)

  // staging map (verified R0 form): LDS byte j*4096 + tid*16 -> row j*32+(tid>>3),
  // stored chunk tid&7 holds global chunk (tid&7)^(row&7). Pre-swizzled source,
  // linear DMA dest (rule #21).
  const int srow = tid >> 3;                // 0..31
  const int lchunk = (tid & 7) ^ (srow & 7);
  const unsigned short* gA = Wp    + (size_t)(r0 + srow) * 512 + lchunk * 8;
  const unsigned short* gB = hprev + (size_t)(n0 + srow) * 512 + lchunk * 8;
  char* lA = (char*)As + wv * 1024;
  char* lB = (char*)Bs + wv * 1024;

  f32x4 acc[4][4] = {};

  // fused 3x3 stencil for step t-1 (overlapped with first stage's latency)
  if (t > 0 && tid < 8) {
    int pix = lid * 8 + tid;                // 2048*8 = 16384 exact
    int b = pix >> 10, p = pix & 1023;
    int py = p >> 5, px = p & 31;
    float a = bpost[0];
#pragma unroll
    for (int dy = -1; dy <= 1; ++dy) {
      int nyy = py + dy;
      if ((unsigned)nyy > 31u) continue;
#pragma unroll
      for (int dx = -1; dx <= 1; ++dx) {
        int nx = px + dx;
        if ((unsigned)nx > 31u) continue;
        int j = (dy + 1) * 3 + (dx + 1);
        a += u[((b * 9 + j) << 10) + (nyy << 5) + nx];
      }
    }
    out[((b * T_ + (t - 1)) << 10) + p] = a;
  }

  for (int kc = 0; kc < 512; kc += 64) {
#pragma unroll
    for (int j = 0; j < 4; ++j) {
      gload_lds16(gA + (size_t)(j * 32) * 512 + kc, lA + j * 4096);
      gload_lds16(gB + (size_t)(j * 32) * 512 + kc, lB + j * 4096);
    }
    __syncthreads();

#pragma unroll
    for (int kk = 0; kk < 2; ++kk) {
      short8 af[4], bf_[4];
#pragma unroll
      for (int mi = 0; mi < 4; ++mi) {
        int row = wm * 64 + mi * 16 + l;
        int sidx = row * 64 + (((kk * 4 + q) ^ (row & 7)) * 8);
        af[mi] = *(const short8*)(As + sidx);
      }
#pragma unroll
      for (int ni = 0; ni < 4; ++ni) {
        int row = wn * 64 + ni * 16 + l;
        int sidx = row * 64 + (((kk * 4 + q) ^ (row & 7)) * 8);
        bf_[ni] = *(const short8*)(Bs + sidx);
      }
#pragma unroll
      for (int mi = 0; mi < 4; ++mi)
#pragma unroll
        for (int ni = 0; ni < 4; ++ni)
          acc[mi][ni] = __builtin_amdgcn_mfma_f32_16x16x32_bf16(af[mi], bf_[ni], acc[mi][ni], 0, 0, 0);
    }
    __syncthreads();
  }

  // ---- epilogue: lane's 4 regs of acc[mi][ni] = (i,f,o,g) for one (ch,pos) ----
  float xv[4]; int posL[4]; size_t cbase[4];
#pragma unroll
  for (int ni = 0; ni < 4; ++ni) {
    posL[ni] = wn * 64 + ni * 16 + l;        // 0..127
    int pos = n0 + posL[ni];
    int b = pos >> 10, p = pos & 1023;
    xv[ni] = xin[((b * T_ + t) << 10) + p];
    cbase[ni] = ((size_t)b << 19) + p;       // b*512*1024 + p
  }
#pragma unroll
  for (int mi = 0; mi < 4; ++mi) {
    int chl = wm * 16 + mi * 4 + q;                    // local ch 0..31
    int rg = r0 + wm * 64 + mi * 16 + q * 4;           // global row of reg0
    float4 w0 = *(const float4*)(w0x + rg);
    float4 bb = *(const float4*)(bxv + rg);
    int ch = ch0 + chl;
#pragma unroll
    for (int ni = 0; ni < 4; ++ni) {
      f32x4 g = acc[mi][ni];
      float gi = g[0] + w0.x * xv[ni] + bb.x;
      float gf = g[1] + w0.y * xv[ni] + bb.y;
      float go = g[2] + w0.z * xv[ni] + bb.z;
      float gg = g[3] + w0.w * xv[ni] + bb.w;
      size_t cidx = cbase[ni] + ((size_t)ch << 10);
      float cold = (float)Cst[cidx];
      float cn = sigf(gf) * cold + sigf(gi) + tanhf_(gg);
      float hn = sigf(go) + tanhf_(cn);
      Cst[cidx] = (_Float16)cn;
      // stash [128 pos][32 ch] shorts = 8 KB into As (loop done). Chunk-XOR
      // on (pos>>1): rows are 64 B, so pos parity splits banks and (pos>>1)
      // spreads the 4 chunk slots -> ~2-way (free). Unswizzled would be 8-way.
      As[posL[ni] * 32 + (chl ^ ((((unsigned)posL[ni] >> 1) & 3) << 3))] = f2bf(hn);
    }
  }
  __syncthreads();
  {
    int pl = tid >> 1;                 // 0..127 local pos
    int half = tid & 1;                // 2 chunks each
    const unsigned short* srcrow = As + pl * 32;
    unsigned short* dst = hnext + (size_t)(n0 + pl) * 512 + ch0;
    int key = ((unsigned)pl >> 1) & 3;
#pragma unroll
    for (int i = 0; i < 2; ++i) {
      int ci = half * 2 + i;
      ((uint4*)dst)[ci] = *(const uint4*)(srcrow + ((ci ^ key) << 3));
    }
  }
}

// ---------------- post conv part 1: u[j][pos] = dot_c(h[pos], wpp[j]) ----------------
// 16 lanes per pixel (wave = 4 pixels), lane owns 32 channels.
__global__ __launch_bounds__(256)
void conv_u(const unsigned short* __restrict__ h, const float* __restrict__ wpp,
            float* __restrict__ u) {
  int wid = blockIdx.x * 4 + (threadIdx.x >> 6);   // wave 0..4095
  int lane = threadIdx.x & 63;
  int sub = lane >> 4;              // pixel within wave
  int sl  = lane & 15;
  int pix = wid * 4 + sub;          // 0..16383
  int c0 = sl << 5;                 // 32 ch per lane
  const uint4* hp = (const uint4*)(h + ((size_t)pix << 9) + c0);
  float a[9] = {};
#pragma unroll
  for (int g = 0; g < 4; ++g) {     // 4 groups of 8 channels
    uint4 hv = hp[g];
    float x0 = bflo(hv.x), x1 = bfhi(hv.x), x2 = bflo(hv.y), x3 = bfhi(hv.y);
    float x4 = bflo(hv.z), x5 = bfhi(hv.z), x6 = bflo(hv.w), x7 = bfhi(hv.w);
    int cg = c0 + g * 8;
#pragma unroll
    for (int j = 0; j < 9; ++j) {
      const float4 wa = *(const float4*)(wpp + (j << 9) + cg);
      const float4 wb = *(const float4*)(wpp + (j << 9) + cg + 4);
      a[j] += x0 * wa.x + x1 * wa.y + x2 * wa.z + x3 * wa.w
            + x4 * wb.x + x5 * wb.y + x6 * wb.z + x7 * wb.w;
    }
  }
  int b = pix >> 10, p = pix & 1023;
  float outv = 0.f;
#pragma unroll
  for (int j = 0; j < 9; ++j) {
    float v = a[j];
    v += __shfl_xor(v, 1, 64);
    v += __shfl_xor(v, 2, 64);
    v += __shfl_xor(v, 4, 64);
    v += __shfl_xor(v, 8, 64);      // 16-lane group sum
    if (sl == j) outv = v;
  }
  if (sl < 9)
    u[((b * 9 + sl) << 10) + p] = outv;
}

// standalone 3x3 stencil (used once, for the final step's output)
__global__ __launch_bounds__(256)
void conv_st(const float* __restrict__ u, const float* __restrict__ bpost,
             float* __restrict__ out, int t) {
  int idx = blockIdx.x * 256 + threadIdx.x;        // 0..16383
  int b = idx >> 10, p = idx & 1023;
  int py = p >> 5, px = p & 31;
  float acc = bpost[0];
#pragma unroll
  for (int dy = -1; dy <= 1; ++dy) {
    int ny = py + dy;
    if ((unsigned)ny > 31u) continue;
#pragma unroll
    for (int dx = -1; dx <= 1; ++dx) {
      int nx = px + dx;
      if ((unsigned)nx > 31u) continue;
      int j = (dy + 1) * 3 + (dx + 1);
      acc += u[((b * 9 + j) << 10) + (ny << 5) + nx];
    }
  }
  out[((b * T_ + t) << 10) + p] = acc;
}

// ---------------- launch ----------------
extern "C" void kernel_launch(void* const* d_in, const int* in_sizes, int n_in,
                              void* d_out, int out_size, void* d_ws, size_t ws_size,
                              hipStream_t stream) {
  const float* x     = (const float*)d_in[0];
  const float* Wconv = (const float*)d_in[1];
  const float* bconv = (const float*)d_in[2];
  const float* Wpost = (const float*)d_in[3];
  const float* bpost = (const float*)d_in[4];
  float* out = (float*)d_out;
  char* ws = (char*)d_ws;

  // workspace layout (bytes)
  unsigned short* h0  = (unsigned short*)(ws);                 // 16 MB
  unsigned short* h1  = (unsigned short*)(ws + 16777216);      // 16 MB
  _Float16*       Cst = (_Float16*)(ws + 33554432);            // 16 MB (fp16 state)
  unsigned short* Wp  = (unsigned short*)(ws + 50331648);      // 2 MB
  float*          w0x = (float*)(ws + 52428800);               // 8 KB
  float*          bx  = (float*)(ws + 52436992);               // 8 KB
  float*          wpp = (float*)(ws + 52445184);               // 18 KB
  float*          u   = (float*)(ws + 52463616);               // 576 KB (16*9*1024 f32)

  hipMemsetAsync(h0, 0, 16777216, stream);
  hipMemsetAsync(Cst, 0, 16777216, stream);
  repack_w<<<4096, 256, 0, stream>>>(Wconv, bconv, Wp, w0x, bx);
  repack_wpost<<<18, 256, 0, stream>>>(Wpost, wpp);

  unsigned short* hp = h0;
  unsigned short* hn = h1;
  for (int t = 0; t < T_; ++t) {
    lstm_step<<<2048, 256, 0, stream>>>(Wp, hp, hn, Cst, w0x, bx, x, u, bpost, out, t);
    conv_u<<<1024, 256, 0, stream>>>(hn, wpp, u);
    unsigned short* tmp = hp; hp = hn; hn = tmp;
  }
  conv_st<<<64, 256, 0, stream>>>(u, bpost, out, T_ - 1);
}